// Round 3
// baseline (599.331 us; speedup 1.0000x reference)
//
#include <hip/hip_runtime.h>
#include <stdint.h>

typedef float f32x4 __attribute__((ext_vector_type(4)));

// One WAVE per TWO 32-bit words, software-pipelined: all 16 loads (8 per word)
// are issued before any use, so word-0's ballot+stores run with word-1's 8 KiB
// still in flight (compiler emits vmcnt(8) before word-0's compute). This
// doubles per-wave MLP and amortizes wave drain/retire over 2 words.
// Lane l's chunk k of word w is the float4 at w*1024 + k*256 + l*4 floats:
// each load/store instruction is a contiguous aligned 1 KiB across 64 lanes.
// No LDS, no barriers, no shuffles; word arithmetic is SALU via __ballot.
__global__ __launch_bounds__(256, 4) void vm_kernel(
    const float* __restrict__ a_bytes,
    const float* __restrict__ b_bytes,
    float* __restrict__ out,
    int n_words)
{
    const int lane = threadIdx.x & 63;
    const int wv   = blockIdx.x * 4 + (threadIdx.x >> 6);
    const int w0   = wv * 2;
    if (w0 >= n_words) return;
    const bool has1 = (w0 + 1) < n_words;   // wave-uniform

    const long base0 = (long)w0 * 1024 + lane * 4;
    const float* pa0 = a_bytes + base0;
    const float* pb0 = b_bytes + base0;
    const float* pa1 = pa0 + 1024;
    const float* pb1 = pb0 + 1024;

    // ---- issue all 16 loads up front ----
    const f32x4 a00 = *(const f32x4*)(pa0);
    const f32x4 a01 = *(const f32x4*)(pa0 + 256);
    const f32x4 a02 = *(const f32x4*)(pa0 + 512);
    const f32x4 a03 = *(const f32x4*)(pa0 + 768);
    const f32x4 b00 = *(const f32x4*)(pb0);
    const f32x4 b01 = *(const f32x4*)(pb0 + 256);
    const f32x4 b02 = *(const f32x4*)(pb0 + 512);
    const f32x4 b03 = *(const f32x4*)(pb0 + 768);

    f32x4 a10 = {0,0,0,0}, a11 = {0,0,0,0}, a12 = {0,0,0,0}, a13 = {0,0,0,0};
    f32x4 b10 = {0,0,0,0}, b11 = {0,0,0,0}, b12 = {0,0,0,0}, b13 = {0,0,0,0};
    if (has1) {
        a10 = *(const f32x4*)(pa1);
        a11 = *(const f32x4*)(pa1 + 256);
        a12 = *(const f32x4*)(pa1 + 512);
        a13 = *(const f32x4*)(pa1 + 768);
        b10 = *(const f32x4*)(pb1);
        b11 = *(const f32x4*)(pb1 + 256);
        b12 = *(const f32x4*)(pb1 + 512);
        b13 = *(const f32x4*)(pb1 + 768);
    }

    // Index of the single 1.0 within a 256-float chunk, via 4 ballots.
    auto idx_of = [&](const f32x4 v) -> uint32_t {
        const uint64_t m0 = __ballot(v.x > 0.5f);
        const uint64_t m1 = __ballot(v.y > 0.5f);
        const uint64_t m2 = __ballot(v.z > 0.5f);
        const uint64_t m3 = __ballot(v.w > 0.5f);
        const uint64_t m  = m0 | m1 | m2 | m3;
        const uint32_t hl = (uint32_t)__ffsll((unsigned long long)m) - 1u;
        const uint32_t c  = (m1 ? 1u : 0u) | (m2 ? 2u : 0u) | (m3 ? 3u : 0u);
        return hl * 4u + c;
    };

    const int j = lane * 4;
    auto emit = [&](uint32_t o, float* po) {
#pragma unroll
        for (int k = 0; k < 4; ++k) {
            const int oi = (int)((o >> (8 * k)) & 255u);
            f32x4 ov;
            ov.x = (j     == oi) ? 1.0f : 0.0f;
            ov.y = (j + 1 == oi) ? 1.0f : 0.0f;
            ov.z = (j + 2 == oi) ? 1.0f : 0.0f;
            ov.w = (j + 3 == oi) ? 1.0f : 0.0f;
            *(f32x4*)(po + k * 256) = ov;
        }
    };

    // ---- word 0: compute + store (word 1's loads still in flight) ----
    {
        const uint32_t aw = idx_of(a00) | (idx_of(a01) << 8) |
                            (idx_of(a02) << 16) | (idx_of(a03) << 24);
        const uint32_t bw = idx_of(b00) | (idx_of(b01) << 8) |
                            (idx_of(b02) << 16) | (idx_of(b03) << 24);
        const uint32_t s = aw + bw;
        emit(s ^ aw, out + base0);
    }

    // ---- word 1 ----
    if (has1) {
        const uint32_t aw = idx_of(a10) | (idx_of(a11) << 8) |
                            (idx_of(a12) << 16) | (idx_of(a13) << 24);
        const uint32_t bw = idx_of(b10) | (idx_of(b11) << 8) |
                            (idx_of(b12) << 16) | (idx_of(b13) << 24);
        const uint32_t s = aw + bw;
        emit(s ^ aw, out + base0 + 1024);
    }
}

extern "C" void kernel_launch(void* const* d_in, const int* in_sizes, int n_in,
                              void* d_out, int out_size, void* d_ws, size_t ws_size,
                              hipStream_t stream)
{
    const float* a_bytes = (const float*)d_in[0];  // [B,4,256]
    const float* b_bytes = (const float*)d_in[1];  // [B,4,256]
    float* out = (float*)d_out;                    // [B,4,256]
    const int n_words = in_sizes[0] / 1024;        // B

    const int blocks = (n_words + 7) / 8;          // 4 waves/block, 2 words/wave
    vm_kernel<<<blocks, 256, 0, stream>>>(a_bytes, b_bytes, out, n_words);
}

// Round 4
// 597.391 us; speedup vs baseline: 1.0032x; 1.0032x over previous
//
#include <hip/hip_runtime.h>
#include <stdint.h>

typedef float f32x4 __attribute__((ext_vector_type(4)));

// ---------------- Phase 1: read-only pass -> 4B/word VM result ----------------
// One wave per word. 8 KiB of coalesced loads, ballot index extraction, SALU
// word arithmetic, then lane 0 stores the final output word (4 B) to ws.
// DRAM sees an (almost) pure READ stream.
__global__ __launch_bounds__(256) void vm_phase1(
    const float* __restrict__ a_bytes,
    const float* __restrict__ b_bytes,
    uint32_t* __restrict__ ws,
    int n_words)
{
    const int lane = threadIdx.x & 63;
    const int w    = blockIdx.x * 4 + (threadIdx.x >> 6);
    if (w >= n_words) return;

    const long base = (long)w * 1024 + lane * 4;
    const float* pa = a_bytes + base;
    const float* pb = b_bytes + base;

    const f32x4 a0 = *(const f32x4*)(pa);
    const f32x4 a1 = *(const f32x4*)(pa + 256);
    const f32x4 a2 = *(const f32x4*)(pa + 512);
    const f32x4 a3 = *(const f32x4*)(pa + 768);
    const f32x4 b0 = *(const f32x4*)(pb);
    const f32x4 b1 = *(const f32x4*)(pb + 256);
    const f32x4 b2 = *(const f32x4*)(pb + 512);
    const f32x4 b3 = *(const f32x4*)(pb + 768);

    auto idx_of = [&](const f32x4 v) -> uint32_t {
        const uint64_t m0 = __ballot(v.x > 0.5f);
        const uint64_t m1 = __ballot(v.y > 0.5f);
        const uint64_t m2 = __ballot(v.z > 0.5f);
        const uint64_t m3 = __ballot(v.w > 0.5f);
        const uint64_t m  = m0 | m1 | m2 | m3;
        const uint32_t hl = (uint32_t)__ffsll((unsigned long long)m) - 1u;
        const uint32_t c  = (m1 ? 1u : 0u) | (m2 ? 2u : 0u) | (m3 ? 3u : 0u);
        return hl * 4u + c;
    };

    const uint32_t aw = idx_of(a0) | (idx_of(a1) << 8) |
                        (idx_of(a2) << 16) | (idx_of(a3) << 24);
    const uint32_t bw = idx_of(b0) | (idx_of(b1) << 8) |
                        (idx_of(b2) << 16) | (idx_of(b3) << 24);
    const uint32_t s = aw + bw;   // ripple-carry add; carry out of byte 3 dropped
    const uint32_t o = s ^ aw;    // chained per-byte XOR with operand a

    if (lane == 0) ws[w] = o;
}

// ---------------- Phase 2: write-only expansion to one-hot ----------------
// One wave per word. 4 B wave-uniform read (scalar load, L2/L3-hot from
// phase 1) -> 4 KiB of coalesced one-hot stores. DRAM sees a pure WRITE stream.
__global__ __launch_bounds__(256) void vm_phase2(
    const uint32_t* __restrict__ ws,
    float* __restrict__ out,
    int n_words)
{
    const int lane = threadIdx.x & 63;
    const int w    = blockIdx.x * 4 + (threadIdx.x >> 6);
    if (w >= n_words) return;

    const uint32_t o = ws[w];            // wave-uniform -> scalar load
    float* po = out + (long)w * 1024 + lane * 4;
    const int j = lane * 4;
#pragma unroll
    for (int k = 0; k < 4; ++k) {
        const int oi = (int)((o >> (8 * k)) & 255u);
        f32x4 ov;
        ov.x = (j     == oi) ? 1.0f : 0.0f;
        ov.y = (j + 1 == oi) ? 1.0f : 0.0f;
        ov.z = (j + 2 == oi) ? 1.0f : 0.0f;
        ov.w = (j + 3 == oi) ? 1.0f : 0.0f;
        *(f32x4*)(po + k * 256) = ov;
    }
}

// ---------------- Fallback: fused single-pass (R2 kernel) ----------------
__global__ __launch_bounds__(256) void vm_fused(
    const float* __restrict__ a_bytes,
    const float* __restrict__ b_bytes,
    float* __restrict__ out,
    int n_words)
{
    const int lane = threadIdx.x & 63;
    const int w    = blockIdx.x * 4 + (threadIdx.x >> 6);
    if (w >= n_words) return;

    const long base = (long)w * 1024 + lane * 4;
    const float* pa = a_bytes + base;
    const float* pb = b_bytes + base;

    const f32x4 a0 = *(const f32x4*)(pa);
    const f32x4 a1 = *(const f32x4*)(pa + 256);
    const f32x4 a2 = *(const f32x4*)(pa + 512);
    const f32x4 a3 = *(const f32x4*)(pa + 768);
    const f32x4 b0 = *(const f32x4*)(pb);
    const f32x4 b1 = *(const f32x4*)(pb + 256);
    const f32x4 b2 = *(const f32x4*)(pb + 512);
    const f32x4 b3 = *(const f32x4*)(pb + 768);

    auto idx_of = [&](const f32x4 v) -> uint32_t {
        const uint64_t m0 = __ballot(v.x > 0.5f);
        const uint64_t m1 = __ballot(v.y > 0.5f);
        const uint64_t m2 = __ballot(v.z > 0.5f);
        const uint64_t m3 = __ballot(v.w > 0.5f);
        const uint64_t m  = m0 | m1 | m2 | m3;
        const uint32_t hl = (uint32_t)__ffsll((unsigned long long)m) - 1u;
        const uint32_t c  = (m1 ? 1u : 0u) | (m2 ? 2u : 0u) | (m3 ? 3u : 0u);
        return hl * 4u + c;
    };

    const uint32_t aw = idx_of(a0) | (idx_of(a1) << 8) |
                        (idx_of(a2) << 16) | (idx_of(a3) << 24);
    const uint32_t bw = idx_of(b0) | (idx_of(b1) << 8) |
                        (idx_of(b2) << 16) | (idx_of(b3) << 24);
    const uint32_t s = aw + bw;
    const uint32_t o = s ^ aw;

    float* po = out + base;
    const int j = lane * 4;
#pragma unroll
    for (int k = 0; k < 4; ++k) {
        const int oi = (int)((o >> (8 * k)) & 255u);
        f32x4 ov;
        ov.x = (j     == oi) ? 1.0f : 0.0f;
        ov.y = (j + 1 == oi) ? 1.0f : 0.0f;
        ov.z = (j + 2 == oi) ? 1.0f : 0.0f;
        ov.w = (j + 3 == oi) ? 1.0f : 0.0f;
        *(f32x4*)(po + k * 256) = ov;
    }
}

extern "C" void kernel_launch(void* const* d_in, const int* in_sizes, int n_in,
                              void* d_out, int out_size, void* d_ws, size_t ws_size,
                              hipStream_t stream)
{
    const float* a_bytes = (const float*)d_in[0];  // [B,4,256]
    const float* b_bytes = (const float*)d_in[1];  // [B,4,256]
    float* out = (float*)d_out;                    // [B,4,256]
    const int n_words = in_sizes[0] / 1024;        // B
    const int blocks  = (n_words + 3) / 4;         // 4 waves/block, 1 word/wave

    if (d_ws != nullptr && ws_size >= (size_t)n_words * 4) {
        uint32_t* ws = (uint32_t*)d_ws;
        vm_phase1<<<blocks, 256, 0, stream>>>(a_bytes, b_bytes, ws, n_words);
        vm_phase2<<<blocks, 256, 0, stream>>>(ws, out, n_words);
    } else {
        vm_fused<<<blocks, 256, 0, stream>>>(a_bytes, b_bytes, out, n_words);
    }
}

// Round 5
// 571.097 us; speedup vs baseline: 1.0494x; 1.0460x over previous
//
#include <hip/hip_runtime.h>
#include <stdint.h>

typedef float f32x4 __attribute__((ext_vector_type(4)));

// One WAVE per 32-bit word (R2 structure — best measured: 183 us), with FULL
// nontemporal hints: NT loads on both inputs, NT stores on the output.
// Purpose: bypass L3 (MALL) allocation so the DRAM read stream is the full
// sequential 537 MB instead of a ~50%-density pseudo-random subset of missed
// lines (the suspected HBM row-locality killer behind the 2.9 TB/s plateau).
// Lane l's chunk k is the float4 at word_base + k*256 + l*4 floats: every
// load/store instruction is a contiguous aligned 1 KiB across the 64 lanes.
// No LDS, no barriers, no shuffles; word arithmetic is SALU via __ballot.
__global__ __launch_bounds__(256) void vm_kernel(
    const float* __restrict__ a_bytes,
    const float* __restrict__ b_bytes,
    float* __restrict__ out,
    int n_words)
{
    const int lane = threadIdx.x & 63;
    const int w    = blockIdx.x * 4 + (threadIdx.x >> 6);
    if (w >= n_words) return;

    const long base = (long)w * 1024 + lane * 4;
    const float* pa = a_bytes + base;
    const float* pb = b_bytes + base;

    // Issue all 8 loads up front (independent, 1 KiB/instr coalesced), NT.
    const f32x4 a0 = __builtin_nontemporal_load((const f32x4*)(pa));
    const f32x4 a1 = __builtin_nontemporal_load((const f32x4*)(pa + 256));
    const f32x4 a2 = __builtin_nontemporal_load((const f32x4*)(pa + 512));
    const f32x4 a3 = __builtin_nontemporal_load((const f32x4*)(pa + 768));
    const f32x4 b0 = __builtin_nontemporal_load((const f32x4*)(pb));
    const f32x4 b1 = __builtin_nontemporal_load((const f32x4*)(pb + 256));
    const f32x4 b2 = __builtin_nontemporal_load((const f32x4*)(pb + 512));
    const f32x4 b3 = __builtin_nontemporal_load((const f32x4*)(pb + 768));

    // Index of the single 1.0 within a 256-float chunk, via 4 ballots.
    // Exactly one mask is nonzero; index = 4*lane_of_hit + component.
    auto idx_of = [&](const f32x4 v) -> uint32_t {
        const uint64_t m0 = __ballot(v.x > 0.5f);
        const uint64_t m1 = __ballot(v.y > 0.5f);
        const uint64_t m2 = __ballot(v.z > 0.5f);
        const uint64_t m3 = __ballot(v.w > 0.5f);
        const uint64_t m  = m0 | m1 | m2 | m3;
        const uint32_t hl = (uint32_t)__ffsll((unsigned long long)m) - 1u;
        const uint32_t c  = (m1 ? 1u : 0u) | (m2 ? 2u : 0u) | (m3 ? 3u : 0u);
        return hl * 4u + c;
    };

    const uint32_t aw = idx_of(a0) | (idx_of(a1) << 8) |
                        (idx_of(a2) << 16) | (idx_of(a3) << 24);
    const uint32_t bw = idx_of(b0) | (idx_of(b1) << 8) |
                        (idx_of(b2) << 16) | (idx_of(b3) << 24);

    const uint32_t s = aw + bw;   // ripple-carry add; carry out of byte 3 dropped
    const uint32_t o = s ^ aw;    // chained per-byte XOR with operand a

    float* po = out + base;
    const int j = lane * 4;
#pragma unroll
    for (int k = 0; k < 4; ++k) {
        const int oi = (int)((o >> (8 * k)) & 255u);
        f32x4 ov;
        ov.x = (j     == oi) ? 1.0f : 0.0f;
        ov.y = (j + 1 == oi) ? 1.0f : 0.0f;
        ov.z = (j + 2 == oi) ? 1.0f : 0.0f;
        ov.w = (j + 3 == oi) ? 1.0f : 0.0f;
        __builtin_nontemporal_store(ov, (f32x4*)(po + k * 256));
    }
}

extern "C" void kernel_launch(void* const* d_in, const int* in_sizes, int n_in,
                              void* d_out, int out_size, void* d_ws, size_t ws_size,
                              hipStream_t stream)
{
    const float* a_bytes = (const float*)d_in[0];  // [B,4,256]
    const float* b_bytes = (const float*)d_in[1];  // [B,4,256]
    float* out = (float*)d_out;                    // [B,4,256]
    const int n_words = in_sizes[0] / 1024;        // B

    const int blocks = (n_words + 3) / 4;          // one wave (64 thr) per word
    vm_kernel<<<blocks, 256, 0, stream>>>(a_bytes, b_bytes, out, n_words);
}